// Round 8
// baseline (490.892 us; speedup 1.0000x reference)
//
#include <hip/hip_runtime.h>
#include <cstdint>

// ---------- types ----------
typedef __bf16 bf16x8 __attribute__((ext_vector_type(8)));
typedef float f32x4 __attribute__((ext_vector_type(4)));
typedef unsigned int u32x4 __attribute__((ext_vector_type(4)));
typedef unsigned int u32x2 __attribute__((ext_vector_type(2)));
typedef unsigned short u16x4 __attribute__((ext_vector_type(4)));

#define D_MODEL 1024
#define SEQ     2048
#define NBATCH  4
#define NHEAD   16
#define HDIM    64
#define NTOK    (NBATCH * SEQ)   // 8192
#define QSCALE  0.18033688011112042f   // 0.125 * log2(e)

__device__ __forceinline__ unsigned short f2bf(float f) {
  unsigned int u = __builtin_bit_cast(unsigned int, f);
  u += 0x7FFFu + ((u >> 16) & 1u);           // round-to-nearest-even
  return (unsigned short)(u >> 16);
}

__device__ __forceinline__ float bf2f(unsigned short s) {
  return __builtin_bit_cast(float, (unsigned int)s << 16);
}

__device__ __forceinline__ bf16x8 load8bf(const unsigned short* p) {
  return __builtin_bit_cast(bf16x8, *(const u32x4*)p);
}

__device__ __forceinline__ f32x4 mfma16(bf16x8 a, bf16x8 b, f32x4 c) {
  return __builtin_amdgcn_mfma_f32_16x16x32_bf16(a, b, c, 0, 0, 0);
}

// async global->LDS, 16B per lane; LDS dest must be waveBase + lane*16
__device__ __forceinline__ void gload16(const unsigned short* g, unsigned short* l) {
  __builtin_amdgcn_global_load_lds((__attribute__((address_space(1))) void*)g,
                                   (__attribute__((address_space(3))) void*)l, 16, 0, 0);
}

// ---------- batched weight cast+transpose + ln1 in one launch ----------
// blocks 0..12287: 32x32 weight transpose tiles; blocks 12288..20479: ln1 rows.
__global__ __launch_bounds__(256) void tcast_ln(const float* __restrict__ wq,
                                                const float* __restrict__ wk,
                                                const float* __restrict__ wv,
                                                const float* __restrict__ wo,
                                                const float* __restrict__ w1,
                                                const float* __restrict__ w2,
                                                unsigned short* __restrict__ wqkv_t,
                                                unsigned short* __restrict__ wo_t,
                                                unsigned short* __restrict__ w1_t,
                                                unsigned short* __restrict__ w2_t,
                                                const float* __restrict__ x,
                                                const float* __restrict__ g1,
                                                const float* __restrict__ bl1,
                                                unsigned short* __restrict__ h1) {
  const int id = blockIdx.x;
  const int tid = threadIdx.x;
  if (id >= 12288) {           // ---- ln1 ----
    const int row = id - 12288;
    const float4 xv = ((const float4*)(x + (size_t)row * D_MODEL))[tid];
    float s  = xv.x + xv.y + xv.z + xv.w;
    float ss = xv.x * xv.x + xv.y * xv.y + xv.z * xv.z + xv.w * xv.w;
    #pragma unroll
    for (int off = 1; off < 64; off <<= 1) { s += __shfl_xor(s, off); ss += __shfl_xor(ss, off); }
    __shared__ float red[8];
    const int wave = tid >> 6, lane = tid & 63;
    if (lane == 0) { red[wave] = s; red[4 + wave] = ss; }
    __syncthreads();
    s  = red[0] + red[1] + red[2] + red[3];
    ss = red[4] + red[5] + red[6] + red[7];
    const float mu   = s * (1.0f / D_MODEL);
    const float var  = ss * (1.0f / D_MODEL) - mu * mu;
    const float rstd = rsqrtf(var + 1e-5f);
    const float4 gv = ((const float4*)g1)[tid];
    const float4 bv = ((const float4*)bl1)[tid];
    u16x4 o;
    o.x = f2bf((xv.x - mu) * rstd * gv.x + bv.x);
    o.y = f2bf((xv.y - mu) * rstd * gv.y + bv.y);
    o.z = f2bf((xv.z - mu) * rstd * gv.z + bv.z);
    o.w = f2bf((xv.w - mu) * rstd * gv.w + bv.w);
    *(u16x4*)(h1 + (size_t)row * D_MODEL + tid * 4) = o;
    return;
  }
  // ---- weight transpose ----
  const float* in; unsigned short* out; int K, N, k0, n0;
  if (id < 4096) {             // wq/wk/wv/wo: 1024x1024 each
    const int seg = id >> 10, r = id & 1023;
    in  = seg == 0 ? wq : seg == 1 ? wk : seg == 2 ? wv : wo;
    out = seg == 3 ? wo_t : wqkv_t + (size_t)seg * 1024 * 1024;
    K = 1024; N = 1024; n0 = (r & 31) * 32; k0 = (r >> 5) * 32;
  } else if (id < 8192) {      // w1: K=1024 -> N=4096
    const int r = id - 4096;
    in = w1; out = w1_t; K = 1024; N = 4096;
    n0 = (r & 127) * 32; k0 = (r >> 7) * 32;
  } else {                     // w2: K=4096 -> N=1024
    const int r = id - 8192;
    in = w2; out = w2_t; K = 4096; N = 1024;
    n0 = (r & 31) * 32; k0 = (r >> 5) * 32;
  }
  __shared__ float tile[32][33];
  const int tx = tid & 31, ty = tid >> 5;
  #pragma unroll
  for (int j = 0; j < 4; ++j)
    tile[ty + 8 * j][tx] = in[(size_t)(k0 + ty + 8 * j) * N + n0 + tx];
  __syncthreads();
  #pragma unroll
  for (int j = 0; j < 4; ++j)
    out[(size_t)(n0 + ty + 8 * j) * K + k0 + tx] = f2bf(tile[tx][ty + 8 * j]);
}

// ---------- layernorm (D=1024), fp32/bf16 in -> bf16 out ----------
template <int FPIN>
__global__ __launch_bounds__(256) void ln_kernel(const void* __restrict__ xin,
                                                 const float* __restrict__ g,
                                                 const float* __restrict__ bb,
                                                 unsigned short* __restrict__ out) {
  const int row = blockIdx.x, tid = threadIdx.x;
  float4 xv;
  if (FPIN) {
    xv = ((const float4*)((const float*)xin + (size_t)row * D_MODEL))[tid];
  } else {
    const u16x4 bv4 = ((const u16x4*)((const unsigned short*)xin + (size_t)row * D_MODEL))[tid];
    xv.x = bf2f(bv4.x); xv.y = bf2f(bv4.y); xv.z = bf2f(bv4.z); xv.w = bf2f(bv4.w);
  }
  float s  = xv.x + xv.y + xv.z + xv.w;
  float ss = xv.x * xv.x + xv.y * xv.y + xv.z * xv.z + xv.w * xv.w;
  #pragma unroll
  for (int off = 1; off < 64; off <<= 1) { s += __shfl_xor(s, off); ss += __shfl_xor(ss, off); }
  __shared__ float red[8];
  const int wave = tid >> 6, lane = tid & 63;
  if (lane == 0) { red[wave] = s; red[4 + wave] = ss; }
  __syncthreads();
  s  = red[0] + red[1] + red[2] + red[3];
  ss = red[4] + red[5] + red[6] + red[7];
  const float mu   = s * (1.0f / D_MODEL);
  const float var  = ss * (1.0f / D_MODEL) - mu * mu;
  const float rstd = rsqrtf(var + 1e-5f);
  const float4 gv = ((const float4*)g)[tid];
  const float4 bv = ((const float4*)bb)[tid];
  u16x4 o;
  o.x = f2bf((xv.x - mu) * rstd * gv.x + bv.x);
  o.y = f2bf((xv.y - mu) * rstd * gv.y + bv.y);
  o.z = f2bf((xv.z - mu) * rstd * gv.z + bv.z);
  o.w = f2bf((xv.w - mu) * rstd * gv.w + bv.w);
  *(u16x4*)(out + (size_t)row * D_MODEL + tid * 4) = o;
}

// ---------- GEMM: C[M,N] = A[M,K](bf16) * Bt[N,K](bf16)^T ----------
// 128x128 tile, BK=64, chunk-XOR swizzled staging (0 conflicts), XCD-banded order.
// OBF epilogue: LDS-transpose (2 half-passes, 17KB) -> coalesced dwordx4 stores;
// residual applied on the coalesced readback. RES: 0 none, 1 fp32, 2 bf16.
template <bool BIAS, bool RELU, int RES, bool OBF, bool QKV>
__global__ __launch_bounds__(256) void gemm_bt(const unsigned short* __restrict__ A,
                                               const unsigned short* __restrict__ Bt,
                                               const float* __restrict__ bias,
                                               const void* __restrict__ res,
                                               void* __restrict__ out,
                                               unsigned short* __restrict__ qb,
                                               unsigned short* __restrict__ kp,
                                               unsigned short* __restrict__ vt,
                                               int M, int N, int K) {
  __shared__ __align__(16) union SMem {
    struct { unsigned short A[128 * 64]; unsigned short B[128 * 64]; } st;
    unsigned short ep[64 * 136];   // epilogue transpose buffer (17KB)
  } sm;
  unsigned short* As = sm.st.A;
  unsigned short* Bs = sm.st.B;
  const int tid  = threadIdx.x;
  const int lin = blockIdx.y * gridDim.x + blockIdx.x;   // gridDim.y == 64 always
  const int xcd = lin & 7, idx = lin >> 3;
  const int by = xcd * 8 + (idx & 7);
  const int bx = idx >> 3;
  const int row0 = by * 128, col0 = bx * 128;
  const int wave = tid >> 6, lane = tid & 63;
  const int wm = wave >> 1, wn = wave & 1;
  const int l15 = lane & 15, quad = lane >> 4;
  f32x4 acc[4][4] = {};

  const int tr = tid >> 3;                        // base row 0..31
  const int tc = (tid & 7) ^ (tr & 7);            // swizzled source chunk
  const unsigned short* gA = A  + (size_t)(row0 + tr) * K + tc * 8;
  const unsigned short* gB = Bt + (size_t)(col0 + tr) * K + tc * 8;

  const int rowA = (wm * 64 + l15) * 64;
  const int rowB = (wn * 64 + l15) * 64;
  const int swz0 = (quad ^ (l15 & 7)) * 8;
  const int swz1 = ((4 + quad) ^ (l15 & 7)) * 8;

  for (int k0 = 0; k0 < K; k0 += 64) {
    #pragma unroll
    for (int i = 0; i < 4; ++i) {
      gload16(gA + (size_t)(i * 32) * K + k0, As + (i * 256 + tid) * 8);
      gload16(gB + (size_t)(i * 32) * K + k0, Bs + (i * 256 + tid) * 8);
    }
    __syncthreads();
    #pragma unroll
    for (int kf = 0; kf < 2; ++kf) {
      const int swz = kf ? swz1 : swz0;
      bf16x8 af[4], bfr[4];
      #pragma unroll
      for (int t = 0; t < 4; ++t) {
        af[t]  = load8bf(As + rowA + t * 1024 + swz);
        bfr[t] = load8bf(Bs + rowB + t * 1024 + swz);
      }
      #pragma unroll
      for (int i = 0; i < 4; ++i)
        #pragma unroll
        for (int j = 0; j < 4; ++j)
          acc[i][j] = mfma16(af[i], bfr[j], acc[i][j]);
    }
    __syncthreads();
  }

  const size_t rbase = (size_t)row0 + wm * 64 + quad * 4;
  const int cbase = col0 + wn * 64 + l15;
  if (QKV) {
    const int sec = col0 >> 10;           // block-uniform: 0=Q, 1=K, 2=V
    #pragma unroll
    for (int i = 0; i < 4; ++i) {
      #pragma unroll
      for (int j = 0; j < 4; ++j) {
        const int col = cbase + j * 16;
        if (sec == 0) {
          #pragma unroll
          for (int r = 0; r < 4; ++r) {
            const size_t row = rbase + i * 16 + r;
            qb[row * 1024 + col] = f2bf(acc[i][j][r] * QSCALE);
          }
        } else if (sec == 1) {
          const int c2 = col - 1024, hh = c2 >> 6, d = c2 & 63;
          #pragma unroll
          for (int r = 0; r < 4; ++r) {
            const size_t row = rbase + i * 16 + r;
            const int bb = (int)(row >> 11), t = (int)(row & 2047);
            kp[(((size_t)(bb * 16 + hh)) * SEQ + t) * 64 + d] = f2bf(acc[i][j][r]);
          }
        } else {
          const int c2 = col - 2048, hh = c2 >> 6, d = c2 & 63;
          const size_t t0 = rbase + i * 16;
          const int bb = (int)(t0 >> 11);
          u16x4 pk;
          #pragma unroll
          for (int r = 0; r < 4; ++r) pk[r] = f2bf(acc[i][j][r]);
          *(u16x4*)(vt + ((size_t)(bb * 16 + hh) * 64 + d) * SEQ + (t0 & 2047)) = pk;
        }
      }
    }
  } else if (OBF) {
    // ---- LDS-transpose epilogue (bf16 out): 2 half-passes of 64 rows ----
    const int lrbase = wm * 32 + quad * 4;
    const int lcol   = wn * 64 + l15;
    #pragma unroll
    for (int p = 0; p < 2; ++p) {
      if (p) __syncthreads();                 // pass-0 reads done before overwrite
      #pragma unroll
      for (int ii = 0; ii < 2; ++ii) {
        const int i = 2 * p + ii;
        #pragma unroll
        for (int j = 0; j < 4; ++j) {
          const float bval = BIAS ? bias[cbase + j * 16] : 0.0f;
          #pragma unroll
          for (int r = 0; r < 4; ++r) {
            float v = acc[i][j][r];
            if (BIAS) v += bval;
            if (RELU) v = fmaxf(v, 0.0f);
            sm.ep[(lrbase + ii * 16 + r) * 136 + lcol + j * 16] = f2bf(v);
          }
        }
      }
      __syncthreads();
      const int lr = tid >> 2;
      const size_t grow = (size_t)row0 + (lr >> 5) * 64 + p * 32 + (lr & 31);
      #pragma unroll
      for (int cc = 0; cc < 4; ++cc) {
        const int c = (tid & 3) * 4 + cc;
        u32x4 val = *(const u32x4*)&sm.ep[lr * 136 + c * 8];
        if (RES == 1) {
          const float* rp = (const float*)res + grow * N + col0 + c * 8;
          unsigned short tmp[8];
          #pragma unroll
          for (int e = 0; e < 4; ++e) {
            const unsigned int w = val[e];
            tmp[2 * e]     = f2bf(bf2f((unsigned short)(w & 0xFFFFu)) + rp[2 * e]);
            tmp[2 * e + 1] = f2bf(bf2f((unsigned short)(w >> 16))    + rp[2 * e + 1]);
          }
          val = *(const u32x4*)tmp;
        } else if (RES == 2) {
          const unsigned short* rp = (const unsigned short*)res + grow * N + col0 + c * 8;
          const u32x4 rv = *(const u32x4*)rp;
          unsigned short tmp[8];
          #pragma unroll
          for (int e = 0; e < 4; ++e) {
            const unsigned int w = val[e], rw = rv[e];
            tmp[2 * e]     = f2bf(bf2f((unsigned short)(w & 0xFFFFu)) + bf2f((unsigned short)(rw & 0xFFFFu)));
            tmp[2 * e + 1] = f2bf(bf2f((unsigned short)(w >> 16))    + bf2f((unsigned short)(rw >> 16)));
          }
          val = *(const u32x4*)tmp;
        }
        *(u32x4*)((unsigned short*)out + grow * N + col0 + c * 8) = val;
      }
    }
  } else {
    // ---- scalar epilogue (fp32 out) ----
    #pragma unroll
    for (int i = 0; i < 4; ++i) {
      #pragma unroll
      for (int j = 0; j < 4; ++j) {
        const int col = cbase + j * 16;
        const float bval = BIAS ? bias[col] : 0.0f;
        #pragma unroll
        for (int r = 0; r < 4; ++r) {
          const size_t row = rbase + i * 16 + r;
          float v = acc[i][j][r];
          if (BIAS) v += bval;
          if (RELU) v = fmaxf(v, 0.0f);
          if (RES == 1) v += ((const float*)res)[row * N + col];
          if (RES == 2) v += bf2f(((const unsigned short*)res)[row * N + col]);
          ((float*)out)[row * N + col] = v;
        }
      }
    }
  }
}

// ---------- fused causal attention v5 ----------
// QK^T with swapped operands (A=K, B=Q): key on rows, query on lanes -> in-lane
// lsum, packed ds_write_b64 P stores. Fixed-max softmax, triangle pairing,
// XCD swizzle. Q pre-scaled by QSCALE in the QKV GEMM epilogue.
__global__ __launch_bounds__(256) void attn5(const unsigned short* __restrict__ qb,
                                             const unsigned short* __restrict__ kp,
                                             const unsigned short* __restrict__ vt,
                                             unsigned short* __restrict__ attnb) {
  const int lin = (blockIdx.z * 16 + blockIdx.y) * 8 + blockIdx.x;  // 512 blocks
  const int xcd = lin & 7, idx = lin >> 3;
  const int bh = xcd * 8 + (idx >> 3);
  const int xb = idx & 7;
  const int b = bh >> 4, h = bh & 15;
  const int tid = threadIdx.x, wave = tid >> 6, lane = tid & 63;
  const int l15 = lane & 15, quad = lane >> 4;
  const size_t tokbase = (size_t)b * SEQ;

  __shared__ __align__(16) unsigned short ks[64 * 64];
  __shared__ __align__(16) unsigned short vts[64 * 64];
  __shared__ __align__(16) unsigned short plds[4][32 * 64];

  const unsigned short* kbase = kp + (size_t)bh * SEQ * HDIM;
  const unsigned short* vbase = vt + (size_t)bh * HDIM * SEQ;

  for (int half = 0; half < 2; ++half) {
    const int qblk = (half == 0) ? (15 - xb) : xb;
    const int qw0 = qblk * 128 + wave * 32;

    bf16x8 qf[2][2];
    #pragma unroll
    for (int qfi = 0; qfi < 2; ++qfi)
      #pragma unroll
      for (int kf = 0; kf < 2; ++kf)
        qf[qfi][kf] = load8bf(qb + (tokbase + qw0 + qfi * 16 + l15) * 1024
                              + h * HDIM + kf * 32 + quad * 8);

    f32x4 o[2][4] = {};
    float lsum[2] = {0.0f, 0.0f};

    const int ntiles = qblk * 2 + 2;
    for (int kt = 0; kt < ntiles; ++kt) {
      const int k0 = kt * 64;
      __syncthreads();
      #pragma unroll
      for (int i = 0; i < 2; ++i) {          // stage K tile (8KB)
        const int cid = i * 256 + tid;
        const int r = cid >> 3, p = cid & 7, c = p ^ (r & 7);
        gload16(kbase + (size_t)(k0 + r) * HDIM + c * 8, ks + cid * 8);
      }
      #pragma unroll
      for (int i = 0; i < 2; ++i) {          // stage V^T tile (8KB)
        const int cid = i * 256 + tid;
        const int d = cid >> 3, p = cid & 7, c = p ^ (d & 7);
        gload16(vbase + (size_t)d * SEQ + k0 + c * 8, vts + cid * 8);
      }
      __syncthreads();
      if (k0 <= qw0 + 31) {
        f32x4 s[4][2] = {};
        #pragma unroll
        for (int kf = 0; kf < 2; ++kf)
          #pragma unroll
          for (int keyf = 0; keyf < 4; ++keyf) {
            const int row = keyf * 16 + l15;
            const int p = (kf * 4 + quad) ^ (row & 7);
            const bf16x8 kfr = load8bf(ks + row * 64 + p * 8);
            s[keyf][0] = mfma16(kfr, qf[0][kf], s[keyf][0]);
            s[keyf][1] = mfma16(kfr, qf[1][kf], s[keyf][1]);
          }
        #pragma unroll
        for (int qfi = 0; qfi < 2; ++qfi) {
          const int q = qw0 + qfi * 16 + l15;
          const int qloc = qfi * 16 + l15;
          #pragma unroll
          for (int keyf = 0; keyf < 4; ++keyf) {
            unsigned int pw[4];
            #pragma unroll
            for (int r = 0; r < 4; ++r) {
              const int key = k0 + keyf * 16 + quad * 4 + r;
              float p = __builtin_amdgcn_exp2f(s[keyf][qfi][r]);
              p = (key > q) ? 0.0f : p;
              pw[r] = __builtin_bit_cast(unsigned int, p);
              lsum[qfi] += __builtin_bit_cast(float, pw[r] & 0xFFFF0000u);
            }
            u32x2 packed;
            packed.x = (pw[0] >> 16) | (pw[1] & 0xFFFF0000u);
            packed.y = (pw[2] >> 16) | (pw[3] & 0xFFFF0000u);
            const int slot = (keyf * 4 + quad) ^ ((l15 & 7) << 1);
            *(u32x2*)(&plds[wave][qloc * 64 + slot * 4]) = packed;
          }
        }
        __builtin_amdgcn_s_waitcnt(0);
        #pragma unroll
        for (int kf = 0; kf < 2; ++kf) {
          bf16x8 pa[2];
          #pragma unroll
          for (int mf = 0; mf < 2; ++mf) {
            const int lq = mf * 16 + l15;
            const int c = (kf * 4 + quad) ^ (l15 & 7);
            pa[mf] = load8bf(&plds[wave][lq * 64 + c * 8]);
          }
          #pragma unroll
          for (int df = 0; df < 4; ++df) {
            const int row = df * 16 + l15;
            const int p = (kf * 4 + quad) ^ (row & 7);
            const bf16x8 vb = load8bf(vts + row * 64 + p * 8);
            o[0][df] = mfma16(pa[0], vb, o[0][df]);
            o[1][df] = mfma16(pa[1], vb, o[1][df]);
          }
        }
      }
    }
    #pragma unroll
    for (int mf = 0; mf < 2; ++mf) {
      float l = lsum[mf];
      l += __shfl_xor(l, 16);
      l += __shfl_xor(l, 32);
      const float rl = 1.0f / l;
      #pragma unroll
      for (int r = 0; r < 4; ++r) {
        const float rv = __shfl(rl, quad * 4 + r);
        const size_t row = tokbase + qw0 + mf * 16 + quad * 4 + r;
        #pragma unroll
        for (int df = 0; df < 4; ++df)
          attnb[row * D_MODEL + h * HDIM + df * 16 + l15] = f2bf(o[mf][df][r] * rv);
      }
    }
  }
}

// ---------- host ----------
extern "C" void kernel_launch(void* const* d_in, const int* in_sizes, int n_in,
                              void* d_out, int out_size, void* d_ws, size_t ws_size,
                              hipStream_t stream) {
  const float* x    = (const float*)d_in[0];
  const float* wq   = (const float*)d_in[1];
  const float* wk   = (const float*)d_in[2];
  const float* wv   = (const float*)d_in[3];
  const float* wo   = (const float*)d_in[4];
  const float* bo   = (const float*)d_in[5];
  const float* w1   = (const float*)d_in[6];
  const float* b1   = (const float*)d_in[7];
  const float* w2   = (const float*)d_in[8];
  const float* b2   = (const float*)d_in[9];
  const float* g1   = (const float*)d_in[10];
  const float* bl1  = (const float*)d_in[11];
  const float* g2   = (const float*)d_in[12];
  const float* bl2  = (const float*)d_in[13];
  float* out = (float*)d_out;

  char* ws = (char*)d_ws;
  size_t off = 0;
  auto alloc = [&](size_t bytes) { char* p = ws + off; off += (bytes + 255) & ~(size_t)255; return p; };
  unsigned short* wqkv_t = (unsigned short*)alloc((size_t)3072 * 1024 * 2);
  unsigned short* wo_t   = (unsigned short*)alloc((size_t)1024 * 1024 * 2);
  unsigned short* w1_t   = (unsigned short*)alloc((size_t)4096 * 1024 * 2);
  unsigned short* w2_t   = (unsigned short*)alloc((size_t)1024 * 4096 * 2);
  unsigned short* h1     = (unsigned short*)alloc((size_t)NTOK * 1024 * 2);
  unsigned short* kpb    = (unsigned short*)alloc((size_t)NTOK * 1024 * 2);  // K packed
  unsigned short* vtb    = (unsigned short*)alloc((size_t)NTOK * 1024 * 2);  // V^T packed
  unsigned short* attnb  = (unsigned short*)alloc((size_t)NTOK * 1024 * 2);
  unsigned short* h2     = (unsigned short*)alloc((size_t)NTOK * 1024 * 2);
  unsigned short* ffn1   = (unsigned short*)alloc((size_t)NTOK * 4096 * 2);
  // qb aliases attnb (reads precede writes within each attn block, disjoint
  // (row,h)-slices across blocks). x1b aliases h1 (dead after QKV GEMM).
  unsigned short* qb  = attnb;
  unsigned short* x1b = h1;

  // weights transpose + ln1 fused in one launch
  tcast_ln<<<12288 + NTOK, 256, 0, stream>>>(wq, wk, wv, wo, w1, w2,
                                             wqkv_t, wo_t, w1_t, w2_t,
                                             x, g1, bl1, h1);
  // fused QKV: writes qb (pre-scaled Q), kp, vt directly
  gemm_bt<false, false, 0, true, true><<<dim3(24, 64), 256, 0, stream>>>(
      h1, wqkv_t, nullptr, nullptr, nullptr, qb, kpb, vtb, NTOK, 3072, 1024);
  attn5<<<dim3(SEQ / 256, NHEAD, NBATCH), 256, 0, stream>>>(qb, kpb, vtb, attnb);
  // x1 = x + attn @ wo + bo  -> bf16 x1b (LDS-transpose epilogue, fp32 res)
  gemm_bt<true, false, 1, true, false><<<dim3(8, 64), 256, 0, stream>>>(
      attnb, wo_t, bo, x, x1b, nullptr, nullptr, nullptr, NTOK, 1024, 1024);
  ln_kernel<0><<<NTOK, 256, 0, stream>>>(x1b, g2, bl2, h2);
  // ffn1 = relu(h2 @ w1 + b1) -> bf16 (LDS-transpose epilogue)
  gemm_bt<true, true, 0, true, false><<<dim3(32, 64), 256, 0, stream>>>(
      h2, w1_t, b1, nullptr, ffn1, nullptr, nullptr, nullptr, NTOK, 4096, 1024);
  // out = x1b + ffn1 @ w2 + b2 (fp32 out, bf16 residual, scalar epilogue)
  gemm_bt<true, false, 2, false, false><<<dim3(8, 64), 256, 0, stream>>>(
      ffn1, w2_t, b2, x1b, out, nullptr, nullptr, nullptr, NTOK, 1024, 4096);
  (void)in_sizes; (void)n_in; (void)out_size; (void)ws_size;
}